// Round 5
// baseline (472.599 us; speedup 1.0000x reference)
//
#include <hip/hip_runtime.h>
#include <stdint.h>

// Problem constants
#define kB  16384
#define kD  1024
#define kDE 512

typedef __bf16 bf16x8 __attribute__((ext_vector_type(8)));
typedef float  f32x4  __attribute__((ext_vector_type(4)));

__device__ __forceinline__ unsigned short f2bf(float f) {
    union { float f; unsigned u; } v; v.f = f;
    unsigned r = v.u + 0x7FFFu + ((v.u >> 16) & 1u);   // round-to-nearest-even
    return (unsigned short)(r >> 16);
}

__device__ __forceinline__ void async16(unsigned short* lds, const unsigned short* g) {
    __builtin_amdgcn_global_load_lds(
        (const __attribute__((address_space(1))) unsigned int*)g,
        (__attribute__((address_space(3))) unsigned int*)lds, 16, 0, 0);
}

// ---------------- prep: transpose + convert weights to bf16 ----------------
__global__ __launch_bounds__(256) void prep_w(const float* __restrict__ Wsh,
                                              const float* __restrict__ Wsp,
                                              unsigned short* __restrict__ Wt) {
    __shared__ float tile[32][33];
    const int slot = blockIdx.z;
    const int k0 = blockIdx.x * 32;
    const int n0 = blockIdx.y * 32;
    const float* src = (slot < 4) ? (Wsh + (size_t)slot * kD * kDE)
                                  : (Wsp + (size_t)(slot - 4) * kD * kDE);
    const int tx = threadIdx.x, ty = threadIdx.y;
#pragma unroll
    for (int i = 0; i < 4; i++)
        tile[ty + i * 8][tx] = src[(size_t)(k0 + ty + i * 8) * kDE + n0 + tx];
    __syncthreads();
    unsigned short* dst = Wt + (size_t)slot * kDE * kD;
#pragma unroll
    for (int i = 0; i < 4; i++)
        dst[(size_t)(n0 + ty + i * 8) * kD + k0 + tx] = f2bf(tile[tx][ty + i * 8]);
}

// bias concat: bc[t][e][n]  (2*8*512)
__global__ __launch_bounds__(256) void prep_b(const float* __restrict__ bsh,
                                              const float* __restrict__ bsp,
                                              float* __restrict__ bc) {
    int i = blockIdx.x * 256 + threadIdx.x;
    int n = i & 511, e = (i >> 9) & 7, t = i >> 12;
    bc[i] = (e < 4) ? bsh[e * 512 + n] : bsp[(t * 4 + (e - 4)) * 512 + n];
}

// ------------- fused x fp32->bf16 conversion + gate softmax ---------------
__global__ __launch_bounds__(256) void conv_gate(
    const float* __restrict__ x0, const float* __restrict__ x1,
    const float* __restrict__ Wg, const float* __restrict__ bg,
    unsigned short* __restrict__ xb, float* __restrict__ g) {
    const int wid = threadIdx.x >> 6, lane = threadIdx.x & 63;
    const int r = blockIdx.x * 4 + wid;
    const int t = r >> 14, b = r & 16383;
    const float* xrow = (t ? x1 : x0) + (size_t)b * kD;
    unsigned short* xbrow = xb + (size_t)(t * kB + b) * kD;
    const float* Wgt = Wg + t * kD * 8;
    float p[8] = {0.f,0.f,0.f,0.f,0.f,0.f,0.f,0.f};
#pragma unroll
    for (int it = 0; it < 4; it++) {
        const int d0 = it * 256 + lane * 4;
        const float4 v = *(const float4*)(xrow + d0);
        ushort4 h;
        h.x = f2bf(v.x); h.y = f2bf(v.y); h.z = f2bf(v.z); h.w = f2bf(v.w);
        *(ushort4*)(xbrow + d0) = h;
        const float xv[4] = {v.x, v.y, v.z, v.w};
#pragma unroll
        for (int j = 0; j < 4; j++) {
            const float* wrow = Wgt + (size_t)(d0 + j) * 8;
            const float4 wa = *(const float4*)wrow;
            const float4 wb = *(const float4*)(wrow + 4);
            p[0] += xv[j] * wa.x; p[1] += xv[j] * wa.y;
            p[2] += xv[j] * wa.z; p[3] += xv[j] * wa.w;
            p[4] += xv[j] * wb.x; p[5] += xv[j] * wb.y;
            p[6] += xv[j] * wb.z; p[7] += xv[j] * wb.w;
        }
    }
#pragma unroll
    for (int e = 0; e < 8; e++) {
        float v = p[e];
#pragma unroll
        for (int s = 1; s < 64; s <<= 1) v += __shfl_xor(v, s, 64);
        p[e] = v;
    }
    float lg[8];
#pragma unroll
    for (int e = 0; e < 8; e++) lg[e] = p[e] + bg[t * 8 + e];
    float mx = lg[0];
#pragma unroll
    for (int e = 1; e < 8; e++) mx = fmaxf(mx, lg[e]);
    float s = 0.f;
#pragma unroll
    for (int e = 0; e < 8; e++) { lg[e] = __expf(lg[e] - mx); s += lg[e]; }
    const float inv = 1.f / s;
    if (lane == 0) {
        float* gp = g + (size_t)(t * kB + b) * 8;
        float4 g0 = {lg[0]*inv, lg[1]*inv, lg[2]*inv, lg[3]*inv};
        float4 g1 = {lg[4]*inv, lg[5]*inv, lg[6]*inv, lg[7]*inv};
        *(float4*)gp = g0;
        *(float4*)(gp + 4) = g1;
    }
}

// --------------------------- fused MoE GEMM (8-phase, corrected) -----------
// BM=256 rows x BN=256 (4 experts x 64 cols), BK=64, 8 waves (2M x 4N).
// Pipeline invariant: a tile's landing is guaranteed by vmcnt(0) executed in
// the PREVIOUS tile's last phase (loads then have 1-3 phases of slack), so
// every ds_read issued pre-barrier reads only guaranteed data.
__global__ __launch_bounds__(512, 2) void moe_gemm(
    const unsigned short* __restrict__ xb, const unsigned short* __restrict__ Wt,
    const float* __restrict__ g, const float* __restrict__ bc,
    float* __restrict__ out) {
    __shared__ __align__(16) unsigned short As[2][256 * 64];      // 64 KB
    __shared__ __align__(16) unsigned short Bs[2][4 * 64 * 64];   // 64 KB

    // XCD-bijective swizzle: 1024 blocks, 128-contiguous chunk per XCD.
    const int bid = blockIdx.x;
    const int swz = (bid & 7) * 128 + (bid >> 3);
    const int t   = swz >> 9;
    const int rem = swz & 511;
    const int rt  = rem >> 3;
    const int ct  = rem & 7;
    const int rowBase = rt * 256, n0 = ct * 64;

    const int tid = threadIdx.x, wid = tid >> 6, lane = tid & 63;
    const int wr = wid >> 2, wc = wid & 3;
    const int lx = lane & 7, kg = lane >> 4;

    // staging (pre-swizzled global source, linear LDS dest — rule #21)
    const int swzChunk = ((lane & 7) ^ ((lane >> 3) & 7)) * 8;
    const unsigned short* aSrc = xb + (size_t)t * kB * kD +
        (size_t)(rowBase + wid * 8 + (lane >> 3)) * kD + swzChunk;
    const size_t bSrcLane = (size_t)(n0 + wid * 8 + (lane >> 3)) * kD + swzChunk;

    // fragment read bases
    const int rAB = (wr * 128 + (lane & 15)) * 64;   // + m*1024 + chunk*8
    const int rBB = (wc * 16 + (lane & 15)) * 64;    // + e*4096 + chunk*8

    f32x4 acc[4][8];
    f32x4 oacc[8];
    bf16x8 af[8], b0, b1;
#pragma unroll
    for (int m = 0; m < 8; m++) oacc[m] = (f32x4){0.f, 0.f, 0.f, 0.f};

#define STAGE_A(buf, ktn, rnd)                                                 \
    async16(&As[buf][(rnd) * 4096 + wid * 512],                                \
            aSrc + (size_t)(rnd) * 64 * kD + (ktn) * 64);

#define STAGE_B(buf, ktn, gn, e)                                               \
    async16(&Bs[buf][(e) * 4096 + wid * 512],                                  \
            Wt + (size_t)(((gn) ? 4 + t * 4 : 0) + (e)) * (kDE * kD) +         \
                bSrcLane + (ktn) * 64);

#define READ_A(buf, ks)                                                        \
    _Pragma("unroll")                                                          \
    for (int m = 0; m < 8; m++)                                                \
        af[m] = *(const bf16x8*)&As[buf][rAB + m * 1024 +                      \
                                         ((((ks) * 4 + kg) ^ lx) << 3)];

#define READ_B(buf, ks, e, dst)                                                \
    dst = *(const bf16x8*)&Bs[buf][(e) * 4096 + rBB +                          \
                                   ((((ks) * 4 + kg) ^ lx) << 3)];

#define CLUST(eA, eB)                                                          \
    __builtin_amdgcn_s_setprio(1);                                             \
    _Pragma("unroll")                                                          \
    for (int m = 0; m < 8; m++) {                                              \
        acc[eA][m] = __builtin_amdgcn_mfma_f32_16x16x32_bf16(af[m], b0,        \
                                                             acc[eA][m], 0, 0, 0); \
        acc[eB][m] = __builtin_amdgcn_mfma_f32_16x16x32_bf16(af[m], b1,        \
                                                             acc[eB][m], 0, 0, 0); \
    }                                                                          \
    __builtin_amdgcn_s_setprio(0);

#define WAIT_ENTER                                                             \
    asm volatile("s_waitcnt lgkmcnt(0)" ::: "memory");                         \
    __builtin_amdgcn_sched_barrier(0);

#define TILE(cur, nxt, in)                                                     \
    {                                                                          \
        const int ktn_ = (in) & 15;                                            \
        const int gn_  = ((in) >> 4) & 1;                                      \
        /* ph0: experts 0,1 ks0; stage all 4 A-rounds of next tile */          \
        READ_A(cur, 0);                                                        \
        READ_B(cur, 0, 0, b0); READ_B(cur, 0, 1, b1);                          \
        STAGE_A(nxt, ktn_, 0); STAGE_A(nxt, ktn_, 1);                          \
        STAGE_A(nxt, ktn_, 2); STAGE_A(nxt, ktn_, 3);                          \
        __builtin_amdgcn_s_barrier();                                          \
        WAIT_ENTER;                                                            \
        CLUST(0, 1);                                                           \
        __builtin_amdgcn_s_barrier();                                          \
        /* ph1: experts 2,3 ks0; stage B experts 0,1 */                        \
        READ_B(cur, 0, 2, b0); READ_B(cur, 0, 3, b1);                          \
        STAGE_B(nxt, ktn_, gn_, 0); STAGE_B(nxt, ktn_, gn_, 1);                \
        __builtin_amdgcn_s_barrier();                                          \
        WAIT_ENTER;                                                            \
        CLUST(2, 3);                                                           \
        __builtin_amdgcn_s_barrier();                                          \
        /* ph2: experts 0,1 ks1; stage B experts 2,3 */                        \
        READ_A(cur, 1);                                                        \
        READ_B(cur, 1, 0, b0); READ_B(cur, 1, 1, b1);                          \
        STAGE_B(nxt, ktn_, gn_, 2); STAGE_B(nxt, ktn_, gn_, 3);                \
        __builtin_amdgcn_s_barrier();                                          \
        WAIT_ENTER;                                                            \
        CLUST(0, 1);                                                           \
        __builtin_amdgcn_s_barrier();                                          \
        /* ph3: experts 2,3 ks1; GUARANTEE next tile landed (vmcnt before     \
           barrier: loads have 1-3 phases of slack, expected wait ~0) */       \
        READ_B(cur, 1, 2, b0); READ_B(cur, 1, 3, b1);                          \
        asm volatile("s_waitcnt vmcnt(0)" ::: "memory");                       \
        __builtin_amdgcn_s_barrier();                                          \
        WAIT_ENTER;                                                            \
        CLUST(2, 3);                                                           \
        __builtin_amdgcn_s_barrier();                                          \
    }

    // prologue: stage tile 0 (group 0) into buf 0 and drain
    STAGE_A(0, 0, 0); STAGE_A(0, 0, 1); STAGE_A(0, 0, 2); STAGE_A(0, 0, 3);
    STAGE_B(0, 0, 0, 0); STAGE_B(0, 0, 0, 1); STAGE_B(0, 0, 0, 2); STAGE_B(0, 0, 0, 3);
    asm volatile("s_waitcnt vmcnt(0)" ::: "memory");
    __builtin_amdgcn_s_barrier();

    const int col = n0 + wc * 16 + (lane & 15);

    for (int gi = 0; gi < 2; ++gi) {
#pragma unroll
        for (int e = 0; e < 4; e++)
#pragma unroll
            for (int m = 0; m < 8; m++) acc[e][m] = (f32x4){0.f, 0.f, 0.f, 0.f};

        for (int kk = 0; kk < 8; ++kk) {
            const int i = gi * 16 + kk * 2;
            TILE(0, 1, i + 1)
            TILE(1, 0, (i + 2) & 31)
        }

        // fold group gi: oacc += sum_e gate * relu(acc + bias)
        float bv[4];
#pragma unroll
        for (int e = 0; e < 4; e++) bv[e] = bc[(t * 8 + gi * 4 + e) * kDE + col];
        const float* gBase = g + (size_t)t * kB * 8 + gi * 4;
#pragma unroll
        for (int m = 0; m < 8; m++) {
            const int r0 = rowBase + wr * 128 + m * 16 + kg * 4;
#pragma unroll
            for (int q = 0; q < 4; q++) {
                const float4 gq = *(const float4*)(gBase + (size_t)(r0 + q) * 8);
                oacc[m][q] += gq.x * fmaxf(acc[0][m][q] + bv[0], 0.f)
                            + gq.y * fmaxf(acc[1][m][q] + bv[1], 0.f)
                            + gq.z * fmaxf(acc[2][m][q] + bv[2], 0.f)
                            + gq.w * fmaxf(acc[3][m][q] + bv[3], 0.f);
            }
        }
    }
    asm volatile("s_waitcnt vmcnt(0)" ::: "memory");

#undef STAGE_A
#undef STAGE_B
#undef READ_A
#undef READ_B
#undef CLUST
#undef WAIT_ENTER
#undef TILE

    // store out[b][t][de]
#pragma unroll
    for (int m = 0; m < 8; m++) {
        const int r0 = rowBase + wr * 128 + m * 16 + kg * 4;
#pragma unroll
        for (int q = 0; q < 4; q++)
            out[((size_t)(r0 + q) * 2 + t) * kDE + col] = oacc[m][q];
    }
}

extern "C" void kernel_launch(void* const* d_in, const int* in_sizes, int n_in,
                              void* d_out, int out_size, void* d_ws, size_t ws_size,
                              hipStream_t stream) {
    const float* x0  = (const float*)d_in[0];
    const float* x1  = (const float*)d_in[1];
    const float* Wsh = (const float*)d_in[2];
    const float* bsh = (const float*)d_in[3];
    const float* Wsp = (const float*)d_in[4];
    const float* bsp = (const float*)d_in[5];
    const float* Wg  = (const float*)d_in[6];
    const float* bg  = (const float*)d_in[7];
    float* out = (float*)d_out;

    // ws layout (bytes): xb 67108864 | Wt 12582912 | g 1048576 | bc 32768
    char* ws = (char*)d_ws;
    unsigned short* xb = (unsigned short*)ws;
    unsigned short* Wt = (unsigned short*)(ws + 67108864);
    float* g  = (float*)(ws + 67108864 + 12582912);
    float* bc = (float*)(ws + 67108864 + 12582912 + 1048576);

    prep_w<<<dim3(32, 16, 12), dim3(32, 8), 0, stream>>>(Wsh, Wsp, Wt);
    prep_b<<<dim3(32), dim3(256), 0, stream>>>(bsh, bsp, bc);
    conv_gate<<<dim3(8192), dim3(256), 0, stream>>>(x0, x1, Wg, bg, xb, g);
    moe_gemm<<<dim3(1024), dim3(512), 0, stream>>>(xb, Wt, g, bc, out);
}

// Round 6
// 410.384 us; speedup vs baseline: 1.1516x; 1.1516x over previous
//
#include <hip/hip_runtime.h>
#include <stdint.h>

// Problem constants
#define kB  16384
#define kD  1024
#define kDE 512

typedef __bf16 bf16x8 __attribute__((ext_vector_type(8)));
typedef float  f32x4  __attribute__((ext_vector_type(4)));

__device__ __forceinline__ unsigned short f2bf(float f) {
    union { float f; unsigned u; } v; v.f = f;
    unsigned r = v.u + 0x7FFFu + ((v.u >> 16) & 1u);   // round-to-nearest-even
    return (unsigned short)(r >> 16);
}

__device__ __forceinline__ void async16(unsigned short* lds, const unsigned short* g) {
    __builtin_amdgcn_global_load_lds(
        (const __attribute__((address_space(1))) unsigned int*)g,
        (__attribute__((address_space(3))) unsigned int*)lds, 16, 0, 0);
}

// ---------------- prep: transpose + convert weights to bf16 ----------------
// Wt[slot][n=512][k=1024]; 64x64 tiles: 256B contiguous reads, 128B writes.
__global__ __launch_bounds__(256) void prep_w(const float* __restrict__ Wsh,
                                              const float* __restrict__ Wsp,
                                              unsigned short* __restrict__ Wt) {
    __shared__ float tile[64][65];
    const int slot = blockIdx.z;
    const int k0 = blockIdx.x * 64;
    const int n0 = blockIdx.y * 64;
    const float* src = (slot < 4) ? (Wsh + (size_t)slot * kD * kDE)
                                  : (Wsp + (size_t)(slot - 4) * kD * kDE);
    const int tid = threadIdx.x;
    const int lr = tid >> 4, lc = (tid & 15) * 4;   // 16 rows/pass, 4 passes
#pragma unroll
    for (int i = 0; i < 4; i++) {
        const float4 v = *(const float4*)&src[(size_t)(k0 + lr + i * 16) * kDE + n0 + lc];
        tile[lr + i * 16][lc + 0] = v.x;
        tile[lr + i * 16][lc + 1] = v.y;
        tile[lr + i * 16][lc + 2] = v.z;
        tile[lr + i * 16][lc + 3] = v.w;
    }
    __syncthreads();
    const int wn = tid >> 2, wk = (tid & 3) * 16;   // 64 n-rows x 4 k-chunks
    unsigned short* dst = Wt + (size_t)slot * kDE * kD + (size_t)(n0 + wn) * kD + k0 + wk;
#pragma unroll
    for (int j = 0; j < 4; j++) {
        ushort4 h;
        h.x = f2bf(tile[wk + j * 4 + 0][wn]);
        h.y = f2bf(tile[wk + j * 4 + 1][wn]);
        h.z = f2bf(tile[wk + j * 4 + 2][wn]);
        h.w = f2bf(tile[wk + j * 4 + 3][wn]);
        *(ushort4*)(dst + j * 4) = h;
    }
}

// ------------- fused x fp32->bf16 conversion + gate softmax ---------------
__global__ __launch_bounds__(256) void conv_gate(
    const float* __restrict__ x0, const float* __restrict__ x1,
    const float* __restrict__ Wg, const float* __restrict__ bg,
    unsigned short* __restrict__ xb, float* __restrict__ g) {
    const int wid = threadIdx.x >> 6, lane = threadIdx.x & 63;
    const int r = blockIdx.x * 4 + wid;
    const int t = r >> 14, b = r & 16383;
    const float* xrow = (t ? x1 : x0) + (size_t)b * kD;
    unsigned short* xbrow = xb + (size_t)(t * kB + b) * kD;
    const float* Wgt = Wg + t * kD * 8;
    float p[8] = {0.f,0.f,0.f,0.f,0.f,0.f,0.f,0.f};
#pragma unroll
    for (int it = 0; it < 4; it++) {
        const int d0 = it * 256 + lane * 4;
        const float4 v = *(const float4*)(xrow + d0);
        ushort4 h;
        h.x = f2bf(v.x); h.y = f2bf(v.y); h.z = f2bf(v.z); h.w = f2bf(v.w);
        *(ushort4*)(xbrow + d0) = h;
        const float xv[4] = {v.x, v.y, v.z, v.w};
#pragma unroll
        for (int j = 0; j < 4; j++) {
            const float* wrow = Wgt + (size_t)(d0 + j) * 8;
            const float4 wa = *(const float4*)wrow;
            const float4 wb = *(const float4*)(wrow + 4);
            p[0] += xv[j] * wa.x; p[1] += xv[j] * wa.y;
            p[2] += xv[j] * wa.z; p[3] += xv[j] * wa.w;
            p[4] += xv[j] * wb.x; p[5] += xv[j] * wb.y;
            p[6] += xv[j] * wb.z; p[7] += xv[j] * wb.w;
        }
    }
#pragma unroll
    for (int e = 0; e < 8; e++) {
        float v = p[e];
#pragma unroll
        for (int s = 1; s < 64; s <<= 1) v += __shfl_xor(v, s, 64);
        p[e] = v;
    }
    float lg[8];
#pragma unroll
    for (int e = 0; e < 8; e++) lg[e] = p[e] + bg[t * 8 + e];
    float mx = lg[0];
#pragma unroll
    for (int e = 1; e < 8; e++) mx = fmaxf(mx, lg[e]);
    float s = 0.f;
#pragma unroll
    for (int e = 0; e < 8; e++) { lg[e] = __expf(lg[e] - mx); s += lg[e]; }
    const float inv = 1.f / s;
    if (lane == 0) {
        float* gp = g + (size_t)(t * kB + b) * 8;
        float4 g0 = {lg[0]*inv, lg[1]*inv, lg[2]*inv, lg[3]*inv};
        float4 g1 = {lg[4]*inv, lg[5]*inv, lg[6]*inv, lg[7]*inv};
        *(float4*)gp = g0;
        *(float4*)(gp + 4) = g1;
    }
}

// --------------------------- fused MoE GEMM (R1 + x2 unroll) ---------------
// Experts inner: M=128 x (8 experts x 64 cols); 8 waves (2Mx4N); BK=64.
// Double-buffered LDS; counted vmcnt(10); K-loop unrolled x2 so both LDS
// buffer indices are COMPILE-TIME constants (provably disjoint -> compiler
// cannot force a conservative vmcnt(0) drain before the ds_reads).
__global__ __launch_bounds__(512, 2) void moe_gemm(
    const unsigned short* __restrict__ xb, const unsigned short* __restrict__ Wt,
    const float* __restrict__ g, const float* __restrict__ bsh,
    const float* __restrict__ bsp, float* __restrict__ out) {
    __shared__ __align__(16) unsigned short As[2][128 * 64];      // 32 KB
    __shared__ __align__(16) unsigned short Bs[2][8 * 64 * 64];   // 128 KB

    // XCD-bijective swizzle (nwg=2048, %8==0)
    const int bid = blockIdx.x;
    const int swz = (bid & 7) * 256 + (bid >> 3);
    const int ct = swz & 7;
    const int rt = (swz >> 3) & 127;
    const int t  = swz >> 10;
    const int n0 = ct * 64;

    const int tid = threadIdx.x, wid = tid >> 6, lane = tid & 63;
    const int wr = wid >> 2, wc = wid & 3;

    // staging (pre-swizzled global source, linear LDS dest — rule #21)
    const int swzChunk = ((lane & 7) ^ ((lane >> 3) & 7)) * 8;
    const unsigned short* aSrc = xb + (size_t)t * kB * kD +
        (size_t)(rt * 128 + wid * 16 + (lane >> 3)) * kD + swzChunk;
    const int slot = (wid < 4) ? wid : (4 + t * 4 + (wid - 4));
    const unsigned short* bSrc = Wt + (size_t)slot * kDE * kD +
        (size_t)(n0 + (lane >> 3)) * kD + swzChunk;

    // fragment read offsets
    const int rAbase = (wr * 64 + (lane & 15)) * 64;
    const int bOff   = (wc * 16 + (lane & 15)) * 64;
    const int lx     = lane & 7;
    const int kg     = lane >> 4;

    f32x4 acc[8][4];
#pragma unroll
    for (int e = 0; e < 8; e++)
#pragma unroll
        for (int m = 0; m < 4; m++) acc[e][m] = (f32x4){0.f, 0.f, 0.f, 0.f};

#define STAGE(buf, kt)                                                        \
    {                                                                         \
        const int k0_ = (kt) * 64;                                            \
        _Pragma("unroll")                                                     \
        for (int i = 0; i < 2; i++)                                           \
            async16(&As[buf][wid * 1024 + i * 512], aSrc + k0_ + i * 8 * kD); \
        _Pragma("unroll")                                                     \
        for (int j = 0; j < 8; j++)                                           \
            async16(&Bs[buf][wid * 4096 + j * 512], bSrc + k0_ + j * 8 * kD); \
    }

#define COMPUTE(buf)                                                          \
    {                                                                         \
        _Pragma("unroll")                                                     \
        for (int ks = 0; ks < 2; ks++) {                                      \
            const int p8 = ((ks * 4 + kg) ^ lx) * 8;                          \
            bf16x8 af[4];                                                     \
            _Pragma("unroll")                                                 \
            for (int m = 0; m < 4; m++)                                       \
                af[m] = *(const bf16x8*)&As[buf][rAbase + m * 1024 + p8];     \
            _Pragma("unroll")                                                 \
            for (int e = 0; e < 8; e++) {                                     \
                bf16x8 bf = *(const bf16x8*)&Bs[buf][e * 4096 + bOff + p8];   \
                _Pragma("unroll")                                             \
                for (int m = 0; m < 4; m++)                                   \
                    acc[e][m] = __builtin_amdgcn_mfma_f32_16x16x32_bf16(      \
                        af[m], bf, acc[e][m], 0, 0, 0);                       \
            }                                                                 \
        }                                                                     \
    }

    STAGE(0, 0);                                   // 10 loads in flight
    for (int kt2 = 0; kt2 < 8; ++kt2) {
        // even step: stage tile 2k+1 into buf1, compute buf0 (tile 2k)
        STAGE(1, kt2 * 2 + 1);
        asm volatile("s_waitcnt vmcnt(10)" ::: "memory");
        __builtin_amdgcn_s_barrier();
        COMPUTE(0);
        __builtin_amdgcn_s_barrier();
        // odd step: stage tile 2k+2 into buf0, compute buf1 (tile 2k+1)
        STAGE(0, (kt2 * 2 + 2) & 15);              // last iter restages t0 (benign)
        asm volatile("s_waitcnt vmcnt(10)" ::: "memory");
        __builtin_amdgcn_s_barrier();
        COMPUTE(1);
        __builtin_amdgcn_s_barrier();
    }
    asm volatile("s_waitcnt vmcnt(0)" ::: "memory");

#undef STAGE
#undef COMPUTE

    // ---- epilogue: out = sum_e g_e * relu(acc[e] + bias_e), bias direct ----
    const int col = n0 + wc * 16 + (lane & 15);
    float bv[8];
#pragma unroll
    for (int e = 0; e < 8; e++)
        bv[e] = (e < 4) ? bsh[e * kDE + col] : bsp[(t * 4 + (e - 4)) * kDE + col];

#pragma unroll
    for (int m = 0; m < 4; m++) {
        const int r0 = rt * 128 + wr * 64 + m * 16 + kg * 4;
#pragma unroll
        for (int q = 0; q < 4; q++) {
            const float* gp = g + ((size_t)t * kB + r0 + q) * 8;
            const float4 ga = *(const float4*)gp;
            const float4 gb = *(const float4*)(gp + 4);
            float s = ga.x * fmaxf(acc[0][m][q] + bv[0], 0.f)
                    + ga.y * fmaxf(acc[1][m][q] + bv[1], 0.f)
                    + ga.z * fmaxf(acc[2][m][q] + bv[2], 0.f)
                    + ga.w * fmaxf(acc[3][m][q] + bv[3], 0.f)
                    + gb.x * fmaxf(acc[4][m][q] + bv[4], 0.f)
                    + gb.y * fmaxf(acc[5][m][q] + bv[5], 0.f)
                    + gb.z * fmaxf(acc[6][m][q] + bv[6], 0.f)
                    + gb.w * fmaxf(acc[7][m][q] + bv[7], 0.f);
            out[((size_t)(r0 + q) * 2 + t) * kDE + col] = s;
        }
    }
}

extern "C" void kernel_launch(void* const* d_in, const int* in_sizes, int n_in,
                              void* d_out, int out_size, void* d_ws, size_t ws_size,
                              hipStream_t stream) {
    const float* x0  = (const float*)d_in[0];
    const float* x1  = (const float*)d_in[1];
    const float* Wsh = (const float*)d_in[2];
    const float* bsh = (const float*)d_in[3];
    const float* Wsp = (const float*)d_in[4];
    const float* bsp = (const float*)d_in[5];
    const float* Wg  = (const float*)d_in[6];
    const float* bg  = (const float*)d_in[7];
    float* out = (float*)d_out;

    // ws layout (bytes): xb 67108864 | Wt 12582912 | g 1048576
    char* ws = (char*)d_ws;
    unsigned short* xb = (unsigned short*)ws;
    unsigned short* Wt = (unsigned short*)(ws + 67108864);
    float* g  = (float*)(ws + 67108864 + 12582912);

    prep_w<<<dim3(16, 8, 12), dim3(256), 0, stream>>>(Wsh, Wsp, Wt);
    conv_gate<<<dim3(8192), dim3(256), 0, stream>>>(x0, x1, Wg, bg, xb, g);
    moe_gemm<<<dim3(2048), dim3(512), 0, stream>>>(xb, Wt, g, bsh, bsp, out);
}